// Round 1
// baseline (2177.353 us; speedup 1.0000x reference)
//
#include <hip/hip_runtime.h>
#include <cstdint>
#include <cstddef>

#define NTOK 4096
#define DIMD 512
#define HIDH 2048
#define NEXP 8
#define TOPK 2
#define CAP (NTOK*TOPK)   // worst-case rows per expert
#define ROWS 32           // token rows per block
#define HC 64             // H-chunk width
#define NTHR 256
#define XS_LD 516         // padded LDS stride for X rows (words)
#define HS_LD 36          // padded LDS stride for H chunk (transposed), 16B-aligned rows

// jax.nn.gelu default (approximate=True): 0.5x(1+tanh(sqrt(2/pi)(x+0.044715x^3)))
//                                       = x * sigmoid(2*sqrt(2/pi)*(x+0.044715x^3))
__device__ __forceinline__ float gelu_tanh(float x) {
    float z2 = 1.5957691216057308f * fmaf(0.044715f * x, x * x, x);
    return x / (1.f + __expf(-z2));
}

__global__ void build_lists(const int* __restrict__ idx, const float* __restrict__ probs,
                            int* __restrict__ counts, int* __restrict__ tok,
                            float* __restrict__ pr) {
    int i = blockIdx.x * blockDim.x + threadIdx.x;
    if (i >= NTOK * TOPK) return;
    int t = i / TOPK;
    int e = idx[i];
    float p = probs[i];
    int pos = atomicAdd(&counts[e], 1);
    tok[e * CAP + pos] = t;
    pr[e * CAP + pos] = p;
}

__global__ __launch_bounds__(NTHR)
void moe_fused(const float* __restrict__ X,
               const float* __restrict__ W1, const float* __restrict__ B1,
               const float* __restrict__ W2, const float* __restrict__ B2,
               const int* __restrict__ counts, const int* __restrict__ tok,
               const float* __restrict__ pr, float* __restrict__ out)
{
    const int e = blockIdx.y;
    const int cnt = counts[e];
    const int r0 = blockIdx.x * ROWS;
    if (r0 >= cnt) return;
    const int nr = min(ROWS, cnt - r0);

    extern __shared__ float smem[];
    float* Xs = smem;                    // [ROWS][XS_LD]
    float* Hs = smem + ROWS * XS_LD;     // [HC][HS_LD]  (transposed: [hcol][row])

    const int tid = threadIdx.x;

    // ---- gather X rows into LDS (zero-fill tail rows) ----
    for (int i = tid; i < ROWS * (DIMD / 4); i += NTHR) {
        int r = i >> 7;           // / 128
        int c4 = i & 127;
        float4 v = make_float4(0.f, 0.f, 0.f, 0.f);
        if (r < nr) {
            int t = tok[e * CAP + r0 + r];
            v = *(const float4*)(X + (size_t)t * DIMD + c4 * 4);
        }
        *(float4*)(Xs + r * XS_LD + c4 * 4) = v;
    }
    __syncthreads();

    // mappings
    const int hq = tid & 15;   // GEMM1: cols hq*4 .. hq*4+3 of the H-chunk
    const int rp = tid >> 4;   // GEMM1: rows rp*2, rp*2+1
    const int wv = tid >> 6;   // GEMM2: wave id -> rows wv*8 .. wv*8+7
    const int ln = tid & 63;   // GEMM2: cols ln*4..+3 and 256+ln*4..+3

    float yacc[8][8];
    #pragma unroll
    for (int r = 0; r < 8; ++r)
        #pragma unroll
        for (int c = 0; c < 8; ++c) yacc[r][c] = 0.f;

    const float* w1base = W1 + (size_t)e * DIMD * HIDH;
    const float* w2base = W2 + (size_t)e * HIDH * DIMD;
    const float* b1base = B1 + e * HIDH;

    for (int h0 = 0; h0 < HIDH; h0 += HC) {
        // ---- GEMM1: Hs[hc][r] = gelu(Xs . W1[:, h0+hc] + b1) ----
        float acc0[4] = {0.f, 0.f, 0.f, 0.f};
        float acc1[4] = {0.f, 0.f, 0.f, 0.f};
        const float* w1p = w1base + h0 + hq * 4;
        const float* xr0 = Xs + (rp * 2) * XS_LD;
        const float* xr1 = xr0 + XS_LD;
        #pragma unroll 2
        for (int d = 0; d < DIMD; d += 4) {
            float4 xa = *(const float4*)(xr0 + d);
            float4 xb = *(const float4*)(xr1 + d);
            float4 w0 = *(const float4*)(w1p + (size_t)(d + 0) * HIDH);
            float4 w1v = *(const float4*)(w1p + (size_t)(d + 1) * HIDH);
            float4 w2v = *(const float4*)(w1p + (size_t)(d + 2) * HIDH);
            float4 w3v = *(const float4*)(w1p + (size_t)(d + 3) * HIDH);
            float xav[4] = {xa.x, xa.y, xa.z, xa.w};
            float xbv[4] = {xb.x, xb.y, xb.z, xb.w};
            float4 wsv[4] = {w0, w1v, w2v, w3v};
            #pragma unroll
            for (int dd = 0; dd < 4; ++dd) {
                acc0[0] = fmaf(xav[dd], wsv[dd].x, acc0[0]);
                acc0[1] = fmaf(xav[dd], wsv[dd].y, acc0[1]);
                acc0[2] = fmaf(xav[dd], wsv[dd].z, acc0[2]);
                acc0[3] = fmaf(xav[dd], wsv[dd].w, acc0[3]);
                acc1[0] = fmaf(xbv[dd], wsv[dd].x, acc1[0]);
                acc1[1] = fmaf(xbv[dd], wsv[dd].y, acc1[1]);
                acc1[2] = fmaf(xbv[dd], wsv[dd].z, acc1[2]);
                acc1[3] = fmaf(xbv[dd], wsv[dd].w, acc1[3]);
            }
        }
        {
            float4 b1v = *(const float4*)(b1base + h0 + hq * 4);
            float bb[4] = {b1v.x, b1v.y, b1v.z, b1v.w};
            #pragma unroll
            for (int j = 0; j < 4; ++j) {
                Hs[(hq * 4 + j) * HS_LD + rp * 2]     = gelu_tanh(acc0[j] + bb[j]);
                Hs[(hq * 4 + j) * HS_LD + rp * 2 + 1] = gelu_tanh(acc1[j] + bb[j]);
            }
        }
        __syncthreads();

        // ---- GEMM2: yacc += Hs^T . W2[h0:h0+HC, :] ----
        const float* w2p = w2base + (size_t)h0 * DIMD;
        #pragma unroll 4
        for (int hc = 0; hc < HC; ++hc) {
            float4 wA = *(const float4*)(w2p + (size_t)hc * DIMD + ln * 4);
            float4 wB = *(const float4*)(w2p + (size_t)hc * DIMD + 256 + ln * 4);
            float4 hv0 = *(const float4*)(Hs + hc * HS_LD + wv * 8);
            float4 hv1 = *(const float4*)(Hs + hc * HS_LD + wv * 8 + 4);
            float hr[8] = {hv0.x, hv0.y, hv0.z, hv0.w, hv1.x, hv1.y, hv1.z, hv1.w};
            #pragma unroll
            for (int r = 0; r < 8; ++r) {
                yacc[r][0] = fmaf(hr[r], wA.x, yacc[r][0]);
                yacc[r][1] = fmaf(hr[r], wA.y, yacc[r][1]);
                yacc[r][2] = fmaf(hr[r], wA.z, yacc[r][2]);
                yacc[r][3] = fmaf(hr[r], wA.w, yacc[r][3]);
                yacc[r][4] = fmaf(hr[r], wB.x, yacc[r][4]);
                yacc[r][5] = fmaf(hr[r], wB.y, yacc[r][5]);
                yacc[r][6] = fmaf(hr[r], wB.z, yacc[r][6]);
                yacc[r][7] = fmaf(hr[r], wB.w, yacc[r][7]);
            }
        }
        __syncthreads();
    }

    // ---- epilogue: out[t] += p * (y + b2) ----
    const float* b2p = B2 + e * DIMD;
    float4 b2A = *(const float4*)(b2p + ln * 4);
    float4 b2B = *(const float4*)(b2p + 256 + ln * 4);
    float bA[4] = {b2A.x, b2A.y, b2A.z, b2A.w};
    float bB[4] = {b2B.x, b2B.y, b2B.z, b2B.w};
    #pragma unroll
    for (int r = 0; r < 8; ++r) {
        int rg = wv * 8 + r;
        if (rg < nr) {
            int t = tok[e * CAP + r0 + rg];
            float p = pr[e * CAP + r0 + rg];
            float* op = out + (size_t)t * DIMD;
            #pragma unroll
            for (int j = 0; j < 4; ++j) {
                atomicAdd(op + ln * 4 + j,        p * (yacc[r][j] + bA[j]));
                atomicAdd(op + 256 + ln * 4 + j,  p * (yacc[r][4 + j] + bB[j]));
            }
        }
    }
}

extern "C" void kernel_launch(void* const* d_in, const int* in_sizes, int n_in,
                              void* d_out, int out_size, void* d_ws, size_t ws_size,
                              hipStream_t stream) {
    const float* X  = (const float*)d_in[0];
    const float* P  = (const float*)d_in[1];
    const int*   I  = (const int*)d_in[2];
    const float* W1 = (const float*)d_in[3];
    const float* B1 = (const float*)d_in[4];
    const float* W2 = (const float*)d_in[5];
    const float* B2 = (const float*)d_in[6];
    float* out = (float*)d_out;

    char* ws = (char*)d_ws;
    int*   counts = (int*)ws;
    int*   tok    = (int*)(ws + 64);
    float* pr     = (float*)(ws + 64 + (size_t)NEXP * CAP * sizeof(int));

    hipMemsetAsync(counts, 0, NEXP * sizeof(int), stream);
    hipMemsetAsync(d_out, 0, (size_t)out_size * sizeof(float), stream);

    build_lists<<<(NTOK * TOPK + 255) / 256, 256, 0, stream>>>(I, P, counts, tok, pr);

    size_t smem = (size_t)(ROWS * XS_LD + HC * HS_LD) * sizeof(float);
    static bool attr_set = false;
    (void)attr_set;
    hipFuncSetAttribute((const void*)moe_fused,
                        hipFuncAttributeMaxDynamicSharedMemorySize, (int)smem);
    moe_fused<<<dim3(CAP / ROWS, NEXP), NTHR, smem, stream>>>(
        X, W1, B1, W2, B2, counts, tok, pr, out);
}

// Round 2
// 232.115 us; speedup vs baseline: 9.3805x; 9.3805x over previous
//
#include <hip/hip_runtime.h>
#include <cstdint>
#include <cstddef>

#define NTOK 4096
#define DIMD 512
#define HIDH 2048
#define NEXP 8
#define TOPK 2
#define NSLOT (NTOK*TOPK)
#define SLACK 128

#define BM 128
#define BN 128
#define BK 32

typedef short bf16x8_t __attribute__((ext_vector_type(8)));
typedef float f32x4_t  __attribute__((ext_vector_type(4)));

__device__ __forceinline__ unsigned short f2b(float f){
  unsigned int x = __float_as_uint(f);
  unsigned int r = (x + 0x7FFFu + ((x >> 16) & 1u)) >> 16;
  return (unsigned short)r;
}

// jax.nn.gelu default (approximate=True)
__device__ __forceinline__ float gelu_tanh(float x) {
  float z2 = 1.5957691216057308f * fmaf(0.044715f * x, x * x, x);
  return x / (1.f + __expf(-z2));
}

__device__ __forceinline__ void gl_lds16(const void* g, void* l){
  __builtin_amdgcn_global_load_lds((const __attribute__((address_space(1))) void*)g,
                                   (__attribute__((address_space(3))) void*)l, 16, 0, 0);
}

// ---------------- conversion kernels ----------------

__global__ __launch_bounds__(256) void cvt_x(const float* __restrict__ x, unsigned short* __restrict__ xb){
  int i = blockIdx.x*256 + threadIdx.x;
  if (i >= (NTOK*DIMD)/4) return;
  float4 v = ((const float4*)x)[i];
  ushort4 o; o.x=f2b(v.x); o.y=f2b(v.y); o.z=f2b(v.z); o.w=f2b(v.w);
  ((ushort4*)xb)[i] = o;
}

// src: [E][R][C] f32  ->  dst: [E][C][R] bf16   (R,C multiples of 64)
__global__ __launch_bounds__(256) void transpose_cvt(const float* __restrict__ src,
                                                     unsigned short* __restrict__ dst,
                                                     int R, int C){
  int e = blockIdx.z;
  src += (size_t)e*R*C; dst += (size_t)e*R*C;
  int c0 = blockIdx.x*64, r0 = blockIdx.y*64;
  __shared__ float t[64][65];
  int tr = threadIdx.x >> 4, tc = threadIdx.x & 15;
  #pragma unroll
  for (int i=0;i<4;i++){
    int r = tr + i*16;
    float4 v = *(const float4*)(src + (size_t)(r0 + r)*C + c0 + tc*4);
    t[r][tc*4+0]=v.x; t[r][tc*4+1]=v.y; t[r][tc*4+2]=v.z; t[r][tc*4+3]=v.w;
  }
  __syncthreads();
  #pragma unroll
  for (int i=0;i<4;i++){
    int c = tr + i*16;
    ushort4 o;
    o.x = f2b(t[tc*4+0][c]); o.y = f2b(t[tc*4+1][c]);
    o.z = f2b(t[tc*4+2][c]); o.w = f2b(t[tc*4+3][c]);
    *(ushort4*)(dst + (size_t)(c0 + c)*R + r0 + tc*4) = o;
  }
}

// ---------------- dispatch build ----------------
// meta[0..7]=counts, meta[8..15]=fill cursors, meta[16..23]=offsets

__global__ void count_k(const int* __restrict__ I, int* __restrict__ meta){
  int i = blockIdx.x*256+threadIdx.x;
  if (i < NSLOT) atomicAdd(&meta[I[i]], 1);
}
__global__ void scan_k(int* __restrict__ meta){
  if (threadIdx.x==0 && blockIdx.x==0){
    int s=0;
    for(int e=0;e<NEXP;e++){ meta[16+e]=s; s+=meta[e]; }
  }
}
__global__ void fill_k(const int* __restrict__ I, int* __restrict__ meta,
                       int* __restrict__ tokOf, int* __restrict__ rowOf){
  int i = blockIdx.x*256+threadIdx.x;
  if (i < NSLOT){
    int e = I[i];
    int pos = meta[16+e] + atomicAdd(&meta[8+e], 1);
    tokOf[pos] = i >> 1;
    rowOf[i] = pos;
  }
}

// ---------------- GEMM1: H = gelu(Xg . W1 + b1), bf16 out ----------------

__global__ __launch_bounds__(256,2) void gemm1(
    const unsigned short* __restrict__ Xb, const unsigned short* __restrict__ W1t,
    const float* __restrict__ B1, const int* __restrict__ meta,
    const int* __restrict__ tokOf, unsigned short* __restrict__ H)
{
  const int e = blockIdx.z;
  const int cnt = meta[e];
  const int row0 = blockIdx.y * BM;
  if (row0 >= cnt) return;
  const int off = meta[16+e];
  const int h0 = blockIdx.x * BN;

  __shared__ unsigned short As[2][BM*BK];
  __shared__ unsigned short Bs[2][BN*BK];

  const int tid = threadIdx.x;
  const int ar0 = tid >> 2;
  const int kseg = (tid & 3) * 8;
  int s0 = min(off + row0 + ar0,      NSLOT-1);
  int s1 = min(off + row0 + ar0 + 64, NSLOT-1);
  const unsigned short* srcA0 = Xb + (size_t)tokOf[s0]*DIMD + kseg;
  const unsigned short* srcA1 = Xb + (size_t)tokOf[s1]*DIMD + kseg;
  const unsigned short* srcB0 = W1t + ((size_t)e*HIDH + h0 + ar0)*DIMD + kseg;
  const unsigned short* srcB1 = srcB0 + (size_t)64*DIMD;

  const int lane = tid & 63;
  const int wid  = tid >> 6;
  const int wr = (wid >> 1) * 64, wc = (wid & 1) * 64;
  const int l15 = lane & 15, kg = lane >> 4;

  f32x4_t acc[4][4];
  #pragma unroll
  for (int i=0;i<4;i++){
    #pragma unroll
    for (int j=0;j<4;j++) acc[i][j] = (f32x4_t){0.f,0.f,0.f,0.f};
  }

  auto stage = [&](int buf, int k0){
    gl_lds16(srcA0 + k0, &As[buf][tid*8]);
    gl_lds16(srcA1 + k0, &As[buf][2048 + tid*8]);
    gl_lds16(srcB0 + k0, &Bs[buf][tid*8]);
    gl_lds16(srcB1 + k0, &Bs[buf][2048 + tid*8]);
  };

  stage(0, 0);
  __syncthreads();
  int cur = 0;
  for (int t = 0; t < DIMD/BK; ++t){
    if (t+1 < DIMD/BK) stage(cur^1, (t+1)*BK);
    bf16x8_t af[4], bfr[4];
    #pragma unroll
    for (int m=0;m<4;m++)
      af[m] = *(const bf16x8_t*)&As[cur][(wr + m*16 + l15)*BK + kg*8];
    #pragma unroll
    for (int n=0;n<4;n++)
      bfr[n] = *(const bf16x8_t*)&Bs[cur][(wc + n*16 + l15)*BK + kg*8];
    #pragma unroll
    for (int m=0;m<4;m++){
      #pragma unroll
      for (int n=0;n<4;n++)
        acc[m][n] = __builtin_amdgcn_mfma_f32_16x16x32_bf16(af[m], bfr[n], acc[m][n], 0,0,0);
    }
    __syncthreads();
    cur ^= 1;
  }

  const int r4 = (lane >> 4) * 4;
  #pragma unroll
  for (int n=0;n<4;n++){
    int hc = h0 + wc + n*16 + l15;
    float b1v = B1[(size_t)e*HIDH + hc];
    #pragma unroll
    for (int m=0;m<4;m++){
      int rbase = row0 + wr + m*16 + r4;
      #pragma unroll
      for (int r=0;r<4;r++){
        int row = rbase + r;
        if (row < cnt){
          float v = gelu_tanh(acc[m][n][r] + b1v);
          H[(size_t)(off + row)*HIDH + hc] = f2b(v);
        }
      }
    }
  }
}

// ---------------- GEMM2: Y = H . W2, f32 out ----------------

__global__ __launch_bounds__(256,2) void gemm2(
    const unsigned short* __restrict__ H, const unsigned short* __restrict__ W2t,
    const int* __restrict__ meta, float* __restrict__ Y)
{
  const int e = blockIdx.z;
  const int cnt = meta[e];
  const int row0 = blockIdx.y * BM;
  if (row0 >= cnt) return;
  const int off = meta[16+e];
  const int d0 = blockIdx.x * BN;

  __shared__ unsigned short As[2][BM*BK];
  __shared__ unsigned short Bs[2][BN*BK];

  const int tid = threadIdx.x;
  const int ar0 = tid >> 2;
  const int kseg = (tid & 3) * 8;
  const unsigned short* srcA0 = H + (size_t)(off + row0 + ar0)*HIDH + kseg;
  const unsigned short* srcA1 = srcA0 + (size_t)64*HIDH;
  const unsigned short* srcB0 = W2t + ((size_t)e*DIMD + d0 + ar0)*HIDH + kseg;
  const unsigned short* srcB1 = srcB0 + (size_t)64*HIDH;

  const int lane = tid & 63;
  const int wid  = tid >> 6;
  const int wr = (wid >> 1) * 64, wc = (wid & 1) * 64;
  const int l15 = lane & 15, kg = lane >> 4;

  f32x4_t acc[4][4];
  #pragma unroll
  for (int i=0;i<4;i++){
    #pragma unroll
    for (int j=0;j<4;j++) acc[i][j] = (f32x4_t){0.f,0.f,0.f,0.f};
  }

  auto stage = [&](int buf, int k0){
    gl_lds16(srcA0 + k0, &As[buf][tid*8]);
    gl_lds16(srcA1 + k0, &As[buf][2048 + tid*8]);
    gl_lds16(srcB0 + k0, &Bs[buf][tid*8]);
    gl_lds16(srcB1 + k0, &Bs[buf][2048 + tid*8]);
  };

  stage(0, 0);
  __syncthreads();
  int cur = 0;
  for (int t = 0; t < HIDH/BK; ++t){
    if (t+1 < HIDH/BK) stage(cur^1, (t+1)*BK);
    bf16x8_t af[4], bfr[4];
    #pragma unroll
    for (int m=0;m<4;m++)
      af[m] = *(const bf16x8_t*)&As[cur][(wr + m*16 + l15)*BK + kg*8];
    #pragma unroll
    for (int n=0;n<4;n++)
      bfr[n] = *(const bf16x8_t*)&Bs[cur][(wc + n*16 + l15)*BK + kg*8];
    #pragma unroll
    for (int m=0;m<4;m++){
      #pragma unroll
      for (int n=0;n<4;n++)
        acc[m][n] = __builtin_amdgcn_mfma_f32_16x16x32_bf16(af[m], bfr[n], acc[m][n], 0,0,0);
    }
    __syncthreads();
    cur ^= 1;
  }

  const int r4 = (lane >> 4) * 4;
  #pragma unroll
  for (int m=0;m<4;m++){
    int rbase = row0 + wr + m*16 + r4;
    #pragma unroll
    for (int r=0;r<4;r++){
      int row = rbase + r;
      if (row < cnt){
        float* yp = Y + (size_t)(off + row)*DIMD + d0 + wc + l15;
        #pragma unroll
        for (int n=0;n<4;n++) yp[n*16] = acc[m][n][r];
      }
    }
  }
}

// ---------------- reduce: out[t] = sum_k P[t,k]*(Y[row(t,k)] + b2[e]) ----------------

__global__ __launch_bounds__(128) void reduce_k(
    const float* __restrict__ P, const int* __restrict__ I, const int* __restrict__ rowOf,
    const float* __restrict__ Y, const float* __restrict__ B2, float* __restrict__ out)
{
  int t = blockIdx.x; int d4 = threadIdx.x;
  float4 a = make_float4(0.f,0.f,0.f,0.f);
  #pragma unroll
  for (int k=0;k<TOPK;k++){
    int i = t*TOPK + k;
    float p = P[i]; int e = I[i]; int r = rowOf[i];
    float4 y = *(const float4*)(Y + (size_t)r*DIMD + d4*4);
    float4 b = *(const float4*)(B2 + (size_t)e*DIMD + d4*4);
    a.x = fmaf(p, y.x+b.x, a.x); a.y = fmaf(p, y.y+b.y, a.y);
    a.z = fmaf(p, y.z+b.z, a.z); a.w = fmaf(p, y.w+b.w, a.w);
  }
  *(float4*)(out + (size_t)t*DIMD + d4*4) = a;
}

// ================= fallback (round-1 f32 path, used if ws too small) =================

#define CAP (NTOK*TOPK)
#define ROWS 32
#define HC 64
#define NTHR 256
#define XS_LD 516
#define HS_LD 36

__global__ void fb_build(const int* __restrict__ idx, const float* __restrict__ probs,
                         int* __restrict__ counts, int* __restrict__ tok,
                         float* __restrict__ pr) {
    int i = blockIdx.x * blockDim.x + threadIdx.x;
    if (i >= NTOK * TOPK) return;
    int t = i / TOPK;
    int e = idx[i];
    float p = probs[i];
    int pos = atomicAdd(&counts[e], 1);
    tok[e * CAP + pos] = t;
    pr[e * CAP + pos] = p;
}

__global__ __launch_bounds__(NTHR)
void fb_moe(const float* __restrict__ X,
            const float* __restrict__ W1, const float* __restrict__ B1,
            const float* __restrict__ W2, const float* __restrict__ B2,
            const int* __restrict__ counts, const int* __restrict__ tok,
            const float* __restrict__ pr, float* __restrict__ out)
{
    const int e = blockIdx.y;
    const int cnt = counts[e];
    const int r0 = blockIdx.x * ROWS;
    if (r0 >= cnt) return;
    const int nr = min(ROWS, cnt - r0);

    extern __shared__ float smem[];
    float* Xs = smem;
    float* Hs = smem + ROWS * XS_LD;
    const int tid = threadIdx.x;

    for (int i = tid; i < ROWS * (DIMD / 4); i += NTHR) {
        int r = i >> 7;
        int c4 = i & 127;
        float4 v = make_float4(0.f, 0.f, 0.f, 0.f);
        if (r < nr) {
            int t = tok[e * CAP + r0 + r];
            v = *(const float4*)(X + (size_t)t * DIMD + c4 * 4);
        }
        *(float4*)(Xs + r * XS_LD + c4 * 4) = v;
    }
    __syncthreads();

    const int hq = tid & 15;
    const int rp = tid >> 4;
    const int wv = tid >> 6;
    const int ln = tid & 63;

    float yacc[8][8];
    #pragma unroll
    for (int r = 0; r < 8; ++r){
        #pragma unroll
        for (int c = 0; c < 8; ++c) yacc[r][c] = 0.f;
    }

    const float* w1base = W1 + (size_t)e * DIMD * HIDH;
    const float* w2base = W2 + (size_t)e * HIDH * DIMD;
    const float* b1base = B1 + e * HIDH;

    for (int h0 = 0; h0 < HIDH; h0 += HC) {
        float acc0[4] = {0.f, 0.f, 0.f, 0.f};
        float acc1[4] = {0.f, 0.f, 0.f, 0.f};
        const float* w1p = w1base + h0 + hq * 4;
        const float* xr0 = Xs + (rp * 2) * XS_LD;
        const float* xr1 = xr0 + XS_LD;
        #pragma unroll 2
        for (int d = 0; d < DIMD; d += 4) {
            float4 xa = *(const float4*)(xr0 + d);
            float4 xb = *(const float4*)(xr1 + d);
            float4 w0 = *(const float4*)(w1p + (size_t)(d + 0) * HIDH);
            float4 w1v = *(const float4*)(w1p + (size_t)(d + 1) * HIDH);
            float4 w2v = *(const float4*)(w1p + (size_t)(d + 2) * HIDH);
            float4 w3v = *(const float4*)(w1p + (size_t)(d + 3) * HIDH);
            float xav[4] = {xa.x, xa.y, xa.z, xa.w};
            float xbv[4] = {xb.x, xb.y, xb.z, xb.w};
            float4 wsv[4] = {w0, w1v, w2v, w3v};
            #pragma unroll
            for (int dd = 0; dd < 4; ++dd) {
                acc0[0] = fmaf(xav[dd], wsv[dd].x, acc0[0]);
                acc0[1] = fmaf(xav[dd], wsv[dd].y, acc0[1]);
                acc0[2] = fmaf(xav[dd], wsv[dd].z, acc0[2]);
                acc0[3] = fmaf(xav[dd], wsv[dd].w, acc0[3]);
                acc1[0] = fmaf(xbv[dd], wsv[dd].x, acc1[0]);
                acc1[1] = fmaf(xbv[dd], wsv[dd].y, acc1[1]);
                acc1[2] = fmaf(xbv[dd], wsv[dd].z, acc1[2]);
                acc1[3] = fmaf(xbv[dd], wsv[dd].w, acc1[3]);
            }
        }
        {
            float4 b1v = *(const float4*)(b1base + h0 + hq * 4);
            float bb[4] = {b1v.x, b1v.y, b1v.z, b1v.w};
            #pragma unroll
            for (int j = 0; j < 4; ++j) {
                Hs[(hq * 4 + j) * HS_LD + rp * 2]     = gelu_tanh(acc0[j] + bb[j]);
                Hs[(hq * 4 + j) * HS_LD + rp * 2 + 1] = gelu_tanh(acc1[j] + bb[j]);
            }
        }
        __syncthreads();

        const float* w2p = w2base + (size_t)h0 * DIMD;
        #pragma unroll 4
        for (int hc = 0; hc < HC; ++hc) {
            float4 wA = *(const float4*)(w2p + (size_t)hc * DIMD + ln * 4);
            float4 wB = *(const float4*)(w2p + (size_t)hc * DIMD + 256 + ln * 4);
            float4 hv0 = *(const float4*)(Hs + hc * HS_LD + wv * 8);
            float4 hv1 = *(const float4*)(Hs + hc * HS_LD + wv * 8 + 4);
            float hr[8] = {hv0.x, hv0.y, hv0.z, hv0.w, hv1.x, hv1.y, hv1.z, hv1.w};
            #pragma unroll
            for (int r = 0; r < 8; ++r) {
                yacc[r][0] = fmaf(hr[r], wA.x, yacc[r][0]);
                yacc[r][1] = fmaf(hr[r], wA.y, yacc[r][1]);
                yacc[r][2] = fmaf(hr[r], wA.z, yacc[r][2]);
                yacc[r][3] = fmaf(hr[r], wA.w, yacc[r][3]);
                yacc[r][4] = fmaf(hr[r], wB.x, yacc[r][4]);
                yacc[r][5] = fmaf(hr[r], wB.y, yacc[r][5]);
                yacc[r][6] = fmaf(hr[r], wB.z, yacc[r][6]);
                yacc[r][7] = fmaf(hr[r], wB.w, yacc[r][7]);
            }
        }
        __syncthreads();
    }

    const float* b2p = B2 + e * DIMD;
    float4 b2A = *(const float4*)(b2p + ln * 4);
    float4 b2B = *(const float4*)(b2p + 256 + ln * 4);
    float bA[4] = {b2A.x, b2A.y, b2A.z, b2A.w};
    float bB[4] = {b2B.x, b2B.y, b2B.z, b2B.w};
    #pragma unroll
    for (int r = 0; r < 8; ++r) {
        int rg = wv * 8 + r;
        if (rg < nr) {
            int t = tok[e * CAP + r0 + rg];
            float p = pr[e * CAP + r0 + rg];
            float* op = out + (size_t)t * DIMD;
            #pragma unroll
            for (int j = 0; j < 4; ++j) {
                atomicAdd(op + ln * 4 + j,        p * (yacc[r][j] + bA[j]));
                atomicAdd(op + 256 + ln * 4 + j,  p * (yacc[r][4 + j] + bB[j]));
            }
        }
    }
}

// ================= launch =================

extern "C" void kernel_launch(void* const* d_in, const int* in_sizes, int n_in,
                              void* d_out, int out_size, void* d_ws, size_t ws_size,
                              hipStream_t stream) {
    const float* X  = (const float*)d_in[0];
    const float* P  = (const float*)d_in[1];
    const int*   I  = (const int*)d_in[2];
    const float* W1 = (const float*)d_in[3];
    const float* B1 = (const float*)d_in[4];
    const float* W2 = (const float*)d_in[5];
    const float* B2 = (const float*)d_in[6];
    float* out = (float*)d_out;
    char* ws = (char*)d_ws;

    // ---- fast-path workspace layout ----
    size_t cur = 0;
    auto alloc = [&](size_t b){ size_t p = cur; cur += (b + 255) & ~(size_t)255; return p; };
    size_t o_meta = alloc(256);
    size_t o_tok  = alloc((size_t)NSLOT*4);
    size_t o_row  = alloc((size_t)NSLOT*4);
    size_t o_xb   = alloc((size_t)NTOK*DIMD*2);
    size_t o_w1t  = alloc((size_t)NEXP*DIMD*HIDH*2);
    size_t o_w2t  = alloc((size_t)NEXP*DIMD*HIDH*2);
    size_t o_h    = alloc((size_t)(NSLOT+SLACK)*HIDH*2);
    size_t o_y    = alloc((size_t)(NSLOT+SLACK)*DIMD*4);
    size_t need = cur;

    if (ws_size >= need) {
        int* meta = (int*)(ws + o_meta);
        int* tokOf = (int*)(ws + o_tok);
        int* rowOf = (int*)(ws + o_row);
        unsigned short* Xb  = (unsigned short*)(ws + o_xb);
        unsigned short* W1t = (unsigned short*)(ws + o_w1t);
        unsigned short* W2t = (unsigned short*)(ws + o_w2t);
        unsigned short* Hb  = (unsigned short*)(ws + o_h);
        float* Yb = (float*)(ws + o_y);

        hipMemsetAsync(meta, 0, 256, stream);
        cvt_x<<<(NTOK*DIMD/4 + 255)/256, 256, 0, stream>>>(X, Xb);
        transpose_cvt<<<dim3(HIDH/64, DIMD/64, NEXP), 256, 0, stream>>>(W1, W1t, DIMD, HIDH);
        transpose_cvt<<<dim3(DIMD/64, HIDH/64, NEXP), 256, 0, stream>>>(W2, W2t, HIDH, DIMD);
        count_k<<<NSLOT/256, 256, 0, stream>>>(I, meta);
        scan_k<<<1, 64, 0, stream>>>(meta);
        fill_k<<<NSLOT/256, 256, 0, stream>>>(I, meta, tokOf, rowOf);
        gemm1<<<dim3(HIDH/BN, NTOK/BM, NEXP), 256, 0, stream>>>(Xb, W1t, B1, meta, tokOf, Hb);
        gemm2<<<dim3(DIMD/BN, NTOK/BM, NEXP), 256, 0, stream>>>(Hb, W2t, meta, Yb);
        reduce_k<<<NTOK, 128, 0, stream>>>(P, I, rowOf, Yb, B2, out);
    } else {
        // fallback: round-1 f32 path
        int*   counts = (int*)ws;
        int*   tok    = (int*)(ws + 64);
        float* pr     = (float*)(ws + 64 + (size_t)NEXP * CAP * sizeof(int));

        hipMemsetAsync(counts, 0, NEXP * sizeof(int), stream);
        hipMemsetAsync(d_out, 0, (size_t)out_size * sizeof(float), stream);
        fb_build<<<(NTOK * TOPK + 255) / 256, 256, 0, stream>>>(I, P, counts, tok, pr);
        size_t smem = (size_t)(ROWS * XS_LD + HC * HS_LD) * sizeof(float);
        hipFuncSetAttribute((const void*)fb_moe,
                            hipFuncAttributeMaxDynamicSharedMemorySize, (int)smem);
        fb_moe<<<dim3(CAP / ROWS, NEXP), NTHR, smem, stream>>>(
            X, W1, B1, W2, B2, counts, tok, pr, out);
    }
}

// Round 3
// 203.305 us; speedup vs baseline: 10.7098x; 1.1417x over previous
//
#include <hip/hip_runtime.h>
#include <cstdint>
#include <cstddef>

#define NTOK 4096
#define DIMD 512
#define HIDH 2048
#define NEXP 8
#define TOPK 2
#define NSLOT (NTOK*TOPK)
#define SLACK 128
#define YROWS (NSLOT+SLACK)

#define BM 128
#define BN 128
#define BK 32

typedef short bf16x8_t __attribute__((ext_vector_type(8)));
typedef float f32x4_t  __attribute__((ext_vector_type(4)));

__device__ __forceinline__ unsigned short f2b(float f){
  unsigned int x = __float_as_uint(f);
  unsigned int r = (x + 0x7FFFu + ((x >> 16) & 1u)) >> 16;
  return (unsigned short)r;
}

// jax.nn.gelu default (approximate=True)
__device__ __forceinline__ float gelu_tanh(float x) {
  float z2 = 1.5957691216057308f * fmaf(0.044715f * x, x * x, x);
  return x / (1.f + __expf(-z2));
}

__device__ __forceinline__ void gl_lds16(const void* g, void* l){
  __builtin_amdgcn_global_load_lds((const __attribute__((address_space(1))) void*)g,
                                   (__attribute__((address_space(3))) void*)l, 16, 0, 0);
}

// ---------------- conversion kernels ----------------

__global__ __launch_bounds__(256) void cvt_x(const float* __restrict__ x, unsigned short* __restrict__ xb){
  int i = blockIdx.x*256 + threadIdx.x;
  if (i >= (NTOK*DIMD)/4) return;
  float4 v = ((const float4*)x)[i];
  ushort4 o; o.x=f2b(v.x); o.y=f2b(v.y); o.z=f2b(v.z); o.w=f2b(v.w);
  ((ushort4*)xb)[i] = o;
}

// src: [E][R][C] f32  ->  dst: [E][C][R] bf16   (R,C multiples of 64)
__global__ __launch_bounds__(256) void transpose_cvt(const float* __restrict__ src,
                                                     unsigned short* __restrict__ dst,
                                                     int R, int C){
  int e = blockIdx.z;
  src += (size_t)e*R*C; dst += (size_t)e*R*C;
  int c0 = blockIdx.x*64, r0 = blockIdx.y*64;
  __shared__ float t[64][65];
  int tr = threadIdx.x >> 4, tc = threadIdx.x & 15;
  #pragma unroll
  for (int i=0;i<4;i++){
    int r = tr + i*16;
    float4 v = *(const float4*)(src + (size_t)(r0 + r)*C + c0 + tc*4);
    t[r][tc*4+0]=v.x; t[r][tc*4+1]=v.y; t[r][tc*4+2]=v.z; t[r][tc*4+3]=v.w;
  }
  __syncthreads();
  #pragma unroll
  for (int i=0;i<4;i++){
    int c = tr + i*16;
    ushort4 o;
    o.x = f2b(t[tc*4+0][c]); o.y = f2b(t[tc*4+1][c]);
    o.z = f2b(t[tc*4+2][c]); o.w = f2b(t[tc*4+3][c]);
    *(ushort4*)(dst + (size_t)(c0 + c)*R + r0 + tc*4) = o;
  }
}

// ---------------- dispatch build ----------------
// meta[0..7]=counts, meta[8..15]=fill cursors, meta[16..23]=offsets

__global__ void count_k(const int* __restrict__ I, int* __restrict__ meta){
  int i = blockIdx.x*256+threadIdx.x;
  if (i < NSLOT) atomicAdd(&meta[I[i]], 1);
}
__global__ void scan_k(int* __restrict__ meta){
  if (threadIdx.x==0 && blockIdx.x==0){
    int s=0;
    for(int e=0;e<NEXP;e++){ meta[16+e]=s; s+=meta[e]; }
  }
}
__global__ void fill_k(const int* __restrict__ I, int* __restrict__ meta,
                       int* __restrict__ tokOf, int* __restrict__ rowOf){
  int i = blockIdx.x*256+threadIdx.x;
  if (i < NSLOT){
    int e = I[i];
    int pos = meta[16+e] + atomicAdd(&meta[8+e], 1);
    tokOf[pos] = i >> 1;
    rowOf[i] = pos;
  }
}

// ---------------- GEMM1: H = gelu(Xg . W1 + b1), bf16 out ----------------

__global__ __launch_bounds__(256,2) void gemm1(
    const unsigned short* __restrict__ Xb, const unsigned short* __restrict__ W1t,
    const float* __restrict__ B1, const int* __restrict__ meta,
    const int* __restrict__ tokOf, unsigned short* __restrict__ H)
{
  const int e = blockIdx.z;
  const int cnt = meta[e];
  const int row0 = blockIdx.y * BM;
  if (row0 >= cnt) return;
  const int off = meta[16+e];
  const int h0 = blockIdx.x * BN;

  __shared__ unsigned short As[2][BM*BK];
  __shared__ unsigned short Bs[2][BN*BK];

  const int tid = threadIdx.x;
  const int ar0 = tid >> 2;
  const int kseg = (tid & 3) * 8;
  int s0 = min(off + row0 + ar0,      NSLOT-1);
  int s1 = min(off + row0 + ar0 + 64, NSLOT-1);
  const unsigned short* srcA0 = Xb + (size_t)tokOf[s0]*DIMD + kseg;
  const unsigned short* srcA1 = Xb + (size_t)tokOf[s1]*DIMD + kseg;
  const unsigned short* srcB0 = W1t + ((size_t)e*HIDH + h0 + ar0)*DIMD + kseg;
  const unsigned short* srcB1 = srcB0 + (size_t)64*DIMD;

  const int lane = tid & 63;
  const int wid  = tid >> 6;
  const int wr = (wid >> 1) * 64, wc = (wid & 1) * 64;
  const int l15 = lane & 15, kg = lane >> 4;

  f32x4_t acc[4][4];
  #pragma unroll
  for (int i=0;i<4;i++){
    #pragma unroll
    for (int j=0;j<4;j++) acc[i][j] = (f32x4_t){0.f,0.f,0.f,0.f};
  }

  auto stage = [&](int buf, int k0){
    gl_lds16(srcA0 + k0, &As[buf][tid*8]);
    gl_lds16(srcA1 + k0, &As[buf][2048 + tid*8]);
    gl_lds16(srcB0 + k0, &Bs[buf][tid*8]);
    gl_lds16(srcB1 + k0, &Bs[buf][2048 + tid*8]);
  };

  stage(0, 0);
  __syncthreads();
  int cur = 0;
  for (int t = 0; t < DIMD/BK; ++t){
    if (t+1 < DIMD/BK) stage(cur^1, (t+1)*BK);
    bf16x8_t af[4], bfr[4];
    #pragma unroll
    for (int m=0;m<4;m++)
      af[m] = *(const bf16x8_t*)&As[cur][(wr + m*16 + l15)*BK + kg*8];
    #pragma unroll
    for (int n=0;n<4;n++)
      bfr[n] = *(const bf16x8_t*)&Bs[cur][(wc + n*16 + l15)*BK + kg*8];
    #pragma unroll
    for (int m=0;m<4;m++){
      #pragma unroll
      for (int n=0;n<4;n++)
        acc[m][n] = __builtin_amdgcn_mfma_f32_16x16x32_bf16(af[m], bfr[n], acc[m][n], 0,0,0);
    }
    __syncthreads();
    cur ^= 1;
  }

  const int r4 = (lane >> 4) * 4;
  #pragma unroll
  for (int n=0;n<4;n++){
    int hc = h0 + wc + n*16 + l15;
    float b1v = B1[(size_t)e*HIDH + hc];
    #pragma unroll
    for (int m=0;m<4;m++){
      int rbase = row0 + wr + m*16 + r4;
      #pragma unroll
      for (int r=0;r<4;r++){
        int row = rbase + r;
        if (row < cnt){
          float v = gelu_tanh(acc[m][n][r] + b1v);
          H[(size_t)(off + row)*HIDH + hc] = f2b(v);
        }
      }
    }
  }
}

// ---------------- GEMM2 (split-K): Yp[kc] = H[:, kc-chunk] . W2[kc-chunk, :] ----------------

__global__ __launch_bounds__(256,2) void gemm2(
    const unsigned short* __restrict__ H, const unsigned short* __restrict__ W2t,
    const int* __restrict__ meta, float* __restrict__ Y, int nsplit)
{
  const int e = blockIdx.z;
  const int cnt = meta[e];
  const int row0 = blockIdx.y * BM;
  if (row0 >= cnt) return;
  const int off = meta[16+e];
  const int ncol = DIMD/BN;
  const int d0 = (blockIdx.x % ncol) * BN;
  const int kc = blockIdx.x / ncol;
  const int kchunk = HIDH / nsplit;
  const int kbase = kc * kchunk;

  __shared__ unsigned short As[2][BM*BK];
  __shared__ unsigned short Bs[2][BN*BK];

  const int tid = threadIdx.x;
  const int ar0 = tid >> 2;
  const int kseg = (tid & 3) * 8;
  const unsigned short* srcA0 = H + (size_t)(off + row0 + ar0)*HIDH + kbase + kseg;
  const unsigned short* srcA1 = srcA0 + (size_t)64*HIDH;
  const unsigned short* srcB0 = W2t + ((size_t)e*DIMD + d0 + ar0)*HIDH + kbase + kseg;
  const unsigned short* srcB1 = srcB0 + (size_t)64*HIDH;

  const int lane = tid & 63;
  const int wid  = tid >> 6;
  const int wr = (wid >> 1) * 64, wc = (wid & 1) * 64;
  const int l15 = lane & 15, kg = lane >> 4;

  f32x4_t acc[4][4];
  #pragma unroll
  for (int i=0;i<4;i++){
    #pragma unroll
    for (int j=0;j<4;j++) acc[i][j] = (f32x4_t){0.f,0.f,0.f,0.f};
  }

  auto stage = [&](int buf, int k0){
    gl_lds16(srcA0 + k0, &As[buf][tid*8]);
    gl_lds16(srcA1 + k0, &As[buf][2048 + tid*8]);
    gl_lds16(srcB0 + k0, &Bs[buf][tid*8]);
    gl_lds16(srcB1 + k0, &Bs[buf][2048 + tid*8]);
  };

  stage(0, 0);
  __syncthreads();
  int cur = 0;
  const int nsteps = kchunk / BK;
  for (int t = 0; t < nsteps; ++t){
    if (t+1 < nsteps) stage(cur^1, (t+1)*BK);
    bf16x8_t af[4], bfr[4];
    #pragma unroll
    for (int m=0;m<4;m++)
      af[m] = *(const bf16x8_t*)&As[cur][(wr + m*16 + l15)*BK + kg*8];
    #pragma unroll
    for (int n=0;n<4;n++)
      bfr[n] = *(const bf16x8_t*)&Bs[cur][(wc + n*16 + l15)*BK + kg*8];
    #pragma unroll
    for (int m=0;m<4;m++){
      #pragma unroll
      for (int n=0;n<4;n++)
        acc[m][n] = __builtin_amdgcn_mfma_f32_16x16x32_bf16(af[m], bfr[n], acc[m][n], 0,0,0);
    }
    __syncthreads();
    cur ^= 1;
  }

  float* Yp = Y + (size_t)kc * YROWS * DIMD;
  const int r4 = (lane >> 4) * 4;
  #pragma unroll
  for (int m=0;m<4;m++){
    int rbase = row0 + wr + m*16 + r4;
    #pragma unroll
    for (int r=0;r<4;r++){
      int row = rbase + r;
      if (row < cnt){
        float* yp = Yp + (size_t)(off + row)*DIMD + d0 + wc + l15;
        #pragma unroll
        for (int n=0;n<4;n++) yp[n*16] = acc[m][n][r];
      }
    }
  }
}

// ------- reduce: out[t] = sum_k P[t,k]*(sum_c Yc[row(t,k)] + b2[e]) -------

__global__ __launch_bounds__(128) void reduce_k(
    const float* __restrict__ P, const int* __restrict__ I, const int* __restrict__ rowOf,
    const float* __restrict__ Y, const float* __restrict__ B2, float* __restrict__ out,
    int nsplit)
{
  int t = blockIdx.x; int d4 = threadIdx.x;
  float4 a = make_float4(0.f,0.f,0.f,0.f);
  #pragma unroll
  for (int k=0;k<TOPK;k++){
    int i = t*TOPK + k;
    float p = P[i]; int e = I[i]; int r = rowOf[i];
    float4 b = *(const float4*)(B2 + (size_t)e*DIMD + d4*4);
    float4 y = make_float4(b.x, b.y, b.z, b.w);
    for (int c=0;c<nsplit;c++){
      float4 v = *(const float4*)(Y + (size_t)c*YROWS*DIMD + (size_t)r*DIMD + d4*4);
      y.x += v.x; y.y += v.y; y.z += v.z; y.w += v.w;
    }
    a.x = fmaf(p, y.x, a.x); a.y = fmaf(p, y.y, a.y);
    a.z = fmaf(p, y.z, a.z); a.w = fmaf(p, y.w, a.w);
  }
  *(float4*)(out + (size_t)t*DIMD + d4*4) = a;
}

// ================= fallback (round-1 f32 path, used if ws too small) =================

#define CAP (NTOK*TOPK)
#define ROWS 32
#define HC 64
#define NTHR 256
#define XS_LD 516
#define HS_LD 36

__global__ void fb_build(const int* __restrict__ idx, const float* __restrict__ probs,
                         int* __restrict__ counts, int* __restrict__ tok,
                         float* __restrict__ pr) {
    int i = blockIdx.x * blockDim.x + threadIdx.x;
    if (i >= NTOK * TOPK) return;
    int t = i / TOPK;
    int e = idx[i];
    float p = probs[i];
    int pos = atomicAdd(&counts[e], 1);
    tok[e * CAP + pos] = t;
    pr[e * CAP + pos] = p;
}

__global__ __launch_bounds__(NTHR)
void fb_moe(const float* __restrict__ X,
            const float* __restrict__ W1, const float* __restrict__ B1,
            const float* __restrict__ W2, const float* __restrict__ B2,
            const int* __restrict__ counts, const int* __restrict__ tok,
            const float* __restrict__ pr, float* __restrict__ out)
{
    const int e = blockIdx.y;
    const int cnt = counts[e];
    const int r0 = blockIdx.x * ROWS;
    if (r0 >= cnt) return;
    const int nr = min(ROWS, cnt - r0);

    extern __shared__ float smem[];
    float* Xs = smem;
    float* Hs = smem + ROWS * XS_LD;
    const int tid = threadIdx.x;

    for (int i = tid; i < ROWS * (DIMD / 4); i += NTHR) {
        int r = i >> 7;
        int c4 = i & 127;
        float4 v = make_float4(0.f, 0.f, 0.f, 0.f);
        if (r < nr) {
            int t = tok[e * CAP + r0 + r];
            v = *(const float4*)(X + (size_t)t * DIMD + c4 * 4);
        }
        *(float4*)(Xs + r * XS_LD + c4 * 4) = v;
    }
    __syncthreads();

    const int hq = tid & 15;
    const int rp = tid >> 4;
    const int wv = tid >> 6;
    const int ln = tid & 63;

    float yacc[8][8];
    #pragma unroll
    for (int r = 0; r < 8; ++r){
        #pragma unroll
        for (int c = 0; c < 8; ++c) yacc[r][c] = 0.f;
    }

    const float* w1base = W1 + (size_t)e * DIMD * HIDH;
    const float* w2base = W2 + (size_t)e * HIDH * DIMD;
    const float* b1base = B1 + e * HIDH;

    for (int h0 = 0; h0 < HIDH; h0 += HC) {
        float acc0[4] = {0.f, 0.f, 0.f, 0.f};
        float acc1[4] = {0.f, 0.f, 0.f, 0.f};
        const float* w1p = w1base + h0 + hq * 4;
        const float* xr0 = Xs + (rp * 2) * XS_LD;
        const float* xr1 = xr0 + XS_LD;
        #pragma unroll 2
        for (int d = 0; d < DIMD; d += 4) {
            float4 xa = *(const float4*)(xr0 + d);
            float4 xb = *(const float4*)(xr1 + d);
            float4 w0 = *(const float4*)(w1p + (size_t)(d + 0) * HIDH);
            float4 w1v = *(const float4*)(w1p + (size_t)(d + 1) * HIDH);
            float4 w2v = *(const float4*)(w1p + (size_t)(d + 2) * HIDH);
            float4 w3v = *(const float4*)(w1p + (size_t)(d + 3) * HIDH);
            float xav[4] = {xa.x, xa.y, xa.z, xa.w};
            float xbv[4] = {xb.x, xb.y, xb.z, xb.w};
            float4 wsv[4] = {w0, w1v, w2v, w3v};
            #pragma unroll
            for (int dd = 0; dd < 4; ++dd) {
                acc0[0] = fmaf(xav[dd], wsv[dd].x, acc0[0]);
                acc0[1] = fmaf(xav[dd], wsv[dd].y, acc0[1]);
                acc0[2] = fmaf(xav[dd], wsv[dd].z, acc0[2]);
                acc0[3] = fmaf(xav[dd], wsv[dd].w, acc0[3]);
                acc1[0] = fmaf(xbv[dd], wsv[dd].x, acc1[0]);
                acc1[1] = fmaf(xbv[dd], wsv[dd].y, acc1[1]);
                acc1[2] = fmaf(xbv[dd], wsv[dd].z, acc1[2]);
                acc1[3] = fmaf(xbv[dd], wsv[dd].w, acc1[3]);
            }
        }
        {
            float4 b1v = *(const float4*)(b1base + h0 + hq * 4);
            float bb[4] = {b1v.x, b1v.y, b1v.z, b1v.w};
            #pragma unroll
            for (int j = 0; j < 4; ++j) {
                Hs[(hq * 4 + j) * HS_LD + rp * 2]     = gelu_tanh(acc0[j] + bb[j]);
                Hs[(hq * 4 + j) * HS_LD + rp * 2 + 1] = gelu_tanh(acc1[j] + bb[j]);
            }
        }
        __syncthreads();

        const float* w2p = w2base + (size_t)h0 * DIMD;
        #pragma unroll 4
        for (int hc = 0; hc < HC; ++hc) {
            float4 wA = *(const float4*)(w2p + (size_t)hc * DIMD + ln * 4);
            float4 wB = *(const float4*)(w2p + (size_t)hc * DIMD + 256 + ln * 4);
            float4 hv0 = *(const float4*)(Hs + hc * HS_LD + wv * 8);
            float4 hv1 = *(const float4*)(Hs + hc * HS_LD + wv * 8 + 4);
            float hr[8] = {hv0.x, hv0.y, hv0.z, hv0.w, hv1.x, hv1.y, hv1.z, hv1.w};
            #pragma unroll
            for (int r = 0; r < 8; ++r) {
                yacc[r][0] = fmaf(hr[r], wA.x, yacc[r][0]);
                yacc[r][1] = fmaf(hr[r], wA.y, yacc[r][1]);
                yacc[r][2] = fmaf(hr[r], wA.z, yacc[r][2]);
                yacc[r][3] = fmaf(hr[r], wA.w, yacc[r][3]);
                yacc[r][4] = fmaf(hr[r], wB.x, yacc[r][4]);
                yacc[r][5] = fmaf(hr[r], wB.y, yacc[r][5]);
                yacc[r][6] = fmaf(hr[r], wB.z, yacc[r][6]);
                yacc[r][7] = fmaf(hr[r], wB.w, yacc[r][7]);
            }
        }
        __syncthreads();
    }

    const float* b2p = B2 + e * DIMD;
    float4 b2A = *(const float4*)(b2p + ln * 4);
    float4 b2B = *(const float4*)(b2p + 256 + ln * 4);
    float bA[4] = {b2A.x, b2A.y, b2A.z, b2A.w};
    float bB[4] = {b2B.x, b2B.y, b2B.z, b2B.w};
    #pragma unroll
    for (int r = 0; r < 8; ++r) {
        int rg = wv * 8 + r;
        if (rg < nr) {
            int t = tok[e * CAP + r0 + rg];
            float p = pr[e * CAP + r0 + rg];
            float* op = out + (size_t)t * DIMD;
            #pragma unroll
            for (int j = 0; j < 4; ++j) {
                atomicAdd(op + ln * 4 + j,        p * (yacc[r][j] + bA[j]));
                atomicAdd(op + 256 + ln * 4 + j,  p * (yacc[r][4 + j] + bB[j]));
            }
        }
    }
}

// ================= launch =================

extern "C" void kernel_launch(void* const* d_in, const int* in_sizes, int n_in,
                              void* d_out, int out_size, void* d_ws, size_t ws_size,
                              hipStream_t stream) {
    const float* X  = (const float*)d_in[0];
    const float* P  = (const float*)d_in[1];
    const int*   I  = (const int*)d_in[2];
    const float* W1 = (const float*)d_in[3];
    const float* B1 = (const float*)d_in[4];
    const float* W2 = (const float*)d_in[5];
    const float* B2 = (const float*)d_in[6];
    float* out = (float*)d_out;
    char* ws = (char*)d_ws;

    // ---- fast-path workspace layout; pick largest split-K that fits ----
    int nsplit = 0;
    size_t o_meta=0, o_tok=0, o_row=0, o_xb=0, o_w1t=0, o_w2t=0, o_h=0, o_y=0;
    const int cand[3] = {4, 2, 1};
    for (int ci = 0; ci < 3; ++ci) {
        int ns = cand[ci];
        size_t cur = 0;
        auto alloc = [&](size_t b){ size_t p = cur; cur += (b + 255) & ~(size_t)255; return p; };
        size_t m_ = alloc(256);
        size_t t_ = alloc((size_t)NSLOT*4);
        size_t r_ = alloc((size_t)NSLOT*4);
        size_t x_ = alloc((size_t)NTOK*DIMD*2);
        size_t w1_ = alloc((size_t)NEXP*DIMD*HIDH*2);
        size_t w2_ = alloc((size_t)NEXP*DIMD*HIDH*2);
        size_t h_ = alloc((size_t)YROWS*HIDH*2);
        size_t y_ = alloc((size_t)ns*YROWS*DIMD*4);
        if (cur <= ws_size) {
            nsplit = ns;
            o_meta=m_; o_tok=t_; o_row=r_; o_xb=x_; o_w1t=w1_; o_w2t=w2_; o_h=h_; o_y=y_;
            break;
        }
    }

    if (nsplit > 0) {
        int* meta = (int*)(ws + o_meta);
        int* tokOf = (int*)(ws + o_tok);
        int* rowOf = (int*)(ws + o_row);
        unsigned short* Xb  = (unsigned short*)(ws + o_xb);
        unsigned short* W1t = (unsigned short*)(ws + o_w1t);
        unsigned short* W2t = (unsigned short*)(ws + o_w2t);
        unsigned short* Hb  = (unsigned short*)(ws + o_h);
        float* Yb = (float*)(ws + o_y);

        hipMemsetAsync(meta, 0, 256, stream);
        cvt_x<<<(NTOK*DIMD/4 + 255)/256, 256, 0, stream>>>(X, Xb);
        transpose_cvt<<<dim3(HIDH/64, DIMD/64, NEXP), 256, 0, stream>>>(W1, W1t, DIMD, HIDH);
        transpose_cvt<<<dim3(DIMD/64, HIDH/64, NEXP), 256, 0, stream>>>(W2, W2t, HIDH, DIMD);
        count_k<<<NSLOT/256, 256, 0, stream>>>(I, meta);
        scan_k<<<1, 64, 0, stream>>>(meta);
        fill_k<<<NSLOT/256, 256, 0, stream>>>(I, meta, tokOf, rowOf);
        gemm1<<<dim3(HIDH/BN, NTOK/BM, NEXP), 256, 0, stream>>>(Xb, W1t, B1, meta, tokOf, Hb);
        gemm2<<<dim3((DIMD/BN)*nsplit, NTOK/BM, NEXP), 256, 0, stream>>>(Hb, W2t, meta, Yb, nsplit);
        reduce_k<<<NTOK, 128, 0, stream>>>(P, I, rowOf, Yb, B2, out, nsplit);
    } else {
        // fallback: round-1 f32 path
        int*   counts = (int*)ws;
        int*   tok    = (int*)(ws + 64);
        float* pr     = (float*)(ws + 64 + (size_t)NEXP * CAP * sizeof(int));

        hipMemsetAsync(counts, 0, NEXP * sizeof(int), stream);
        hipMemsetAsync(d_out, 0, (size_t)out_size * sizeof(float), stream);
        fb_build<<<(NTOK * TOPK + 255) / 256, 256, 0, stream>>>(I, P, counts, tok, pr);
        size_t smem = (size_t)(ROWS * XS_LD + HC * HS_LD) * sizeof(float);
        hipFuncSetAttribute((const void*)fb_moe,
                            hipFuncAttributeMaxDynamicSharedMemorySize, (int)smem);
        fb_moe<<<dim3(CAP / ROWS, NEXP), NTHR, smem, stream>>>(
            X, W1, B1, W2, B2, counts, tok, pr, out);
    }
}

// Round 4
// 198.391 us; speedup vs baseline: 10.9751x; 1.0248x over previous
//
#include <hip/hip_runtime.h>
#include <cstdint>
#include <cstddef>

#define NTOK 4096
#define DIMD 512
#define HIDH 2048
#define NEXP 8
#define TOPK 2
#define NSLOT (NTOK*TOPK)
#define SLACK 128
#define YROWS (NSLOT+SLACK)

#define BM 128
#define BN 128
#define BK 32

typedef short bf16x8_t __attribute__((ext_vector_type(8)));
typedef float f32x4_t  __attribute__((ext_vector_type(4)));

__device__ __forceinline__ unsigned short f2b(float f){
  unsigned int x = __float_as_uint(f);
  unsigned int r = (x + 0x7FFFu + ((x >> 16) & 1u)) >> 16;
  return (unsigned short)r;
}

// jax.nn.gelu default (approximate=True)
__device__ __forceinline__ float gelu_tanh(float x) {
  float z2 = 1.5957691216057308f * fmaf(0.044715f * x, x * x, x);
  return x / (1.f + __expf(-z2));
}

__device__ __forceinline__ void gl_lds16(const void* g, void* l){
  __builtin_amdgcn_global_load_lds((const __attribute__((address_space(1))) void*)g,
                                   (__attribute__((address_space(3))) void*)l, 16, 0, 0);
}

// ---------------- conversion kernels ----------------

__global__ __launch_bounds__(256) void cvt_x(const float* __restrict__ x, unsigned short* __restrict__ xb){
  int i = blockIdx.x*256 + threadIdx.x;
  if (i >= (NTOK*DIMD)/4) return;
  float4 v = ((const float4*)x)[i];
  ushort4 o; o.x=f2b(v.x); o.y=f2b(v.y); o.z=f2b(v.z); o.w=f2b(v.w);
  ((ushort4*)xb)[i] = o;
}

// src: [E][R][C] f32  ->  dst: [E][C][R] bf16   (R,C multiples of 64)
__global__ __launch_bounds__(256) void transpose_cvt(const float* __restrict__ src,
                                                     unsigned short* __restrict__ dst,
                                                     int R, int C){
  int e = blockIdx.z;
  src += (size_t)e*R*C; dst += (size_t)e*R*C;
  int c0 = blockIdx.x*64, r0 = blockIdx.y*64;
  __shared__ float t[64][65];
  int tr = threadIdx.x >> 4, tc = threadIdx.x & 15;
  #pragma unroll
  for (int i=0;i<4;i++){
    int r = tr + i*16;
    float4 v = *(const float4*)(src + (size_t)(r0 + r)*C + c0 + tc*4);
    t[r][tc*4+0]=v.x; t[r][tc*4+1]=v.y; t[r][tc*4+2]=v.z; t[r][tc*4+3]=v.w;
  }
  __syncthreads();
  #pragma unroll
  for (int i=0;i<4;i++){
    int c = tr + i*16;
    ushort4 o;
    o.x = f2b(t[tc*4+0][c]); o.y = f2b(t[tc*4+1][c]);
    o.z = f2b(t[tc*4+2][c]); o.w = f2b(t[tc*4+3][c]);
    *(ushort4*)(dst + (size_t)(c0 + c)*R + r0 + tc*4) = o;
  }
}

// ---------------- dispatch build ----------------
// meta[0..7]=counts, meta[8..15]=fill cursors, meta[16..23]=offsets

__global__ void count_k(const int* __restrict__ I, int* __restrict__ meta){
  int i = blockIdx.x*256+threadIdx.x;
  if (i < NSLOT) atomicAdd(&meta[I[i]], 1);
}
__global__ void scan_k(int* __restrict__ meta){
  if (threadIdx.x==0 && blockIdx.x==0){
    int s=0;
    for(int e=0;e<NEXP;e++){ meta[16+e]=s; s+=meta[e]; }
  }
}
__global__ void fill_k(const int* __restrict__ I, int* __restrict__ meta,
                       int* __restrict__ tokOf, int* __restrict__ rowOf){
  int i = blockIdx.x*256+threadIdx.x;
  if (i < NSLOT){
    int e = I[i];
    int pos = meta[16+e] + atomicAdd(&meta[8+e], 1);
    tokOf[pos] = i >> 1;
    rowOf[i] = pos;
  }
}

// ---------------- GEMM1: H = gelu(Xg . W1 + b1), bf16 out ----------------
// 3-deep LDS pipeline, counted vmcnt, XOR-swizzled (source-side) staging.

__global__ __launch_bounds__(256,2) void gemm1(
    const unsigned short* __restrict__ Xb, const unsigned short* __restrict__ W1t,
    const float* __restrict__ B1, const int* __restrict__ meta,
    const int* __restrict__ tokOf, unsigned short* __restrict__ H)
{
  const int e = blockIdx.z;
  const int cnt = meta[e];
  const int row0 = blockIdx.y * BM;
  if (row0 >= cnt) return;
  const int off = meta[16+e];
  const int h0 = blockIdx.x * BN;

  __shared__ unsigned short As[3][BM*BK];
  __shared__ unsigned short Bs[3][BN*BK];

  const int tid = threadIdx.x;
  const int ar0 = tid >> 2;
  // source-side swizzle: chunk j' = j ^ ((row>>1)&3); row = tid>>2
  const int ksw = (((tid & 3) ^ ((tid >> 3) & 3)) << 3);
  int s0 = min(off + row0 + ar0,      NSLOT-1);
  int s1 = min(off + row0 + ar0 + 64, NSLOT-1);
  const unsigned short* srcA0 = Xb + (size_t)tokOf[s0]*DIMD + ksw;
  const unsigned short* srcA1 = Xb + (size_t)tokOf[s1]*DIMD + ksw;
  const unsigned short* srcB0 = W1t + ((size_t)e*HIDH + h0 + ar0)*DIMD + ksw;
  const unsigned short* srcB1 = srcB0 + (size_t)64*DIMD;

  const int lane = tid & 63;
  const int wid  = tid >> 6;
  const int wr = (wid >> 1) * 64, wc = (wid & 1) * 64;
  const int l15 = lane & 15, kg = lane >> 4;

  // swizzled per-lane LDS fragment offsets (elements)
  int offA[4], offB[4];
  #pragma unroll
  for (int m=0;m<4;m++){
    int r  = wr + m*16 + l15;
    int rb = wc + m*16 + l15;
    offA[m] = r *BK + ((kg ^ ((r >>1)&3)) << 3);
    offB[m] = rb*BK + ((kg ^ ((rb>>1)&3)) << 3);
  }

  f32x4_t acc[4][4];
  #pragma unroll
  for (int i=0;i<4;i++){
    #pragma unroll
    for (int j=0;j<4;j++) acc[i][j] = (f32x4_t){0.f,0.f,0.f,0.f};
  }

  auto stage = [&](int buf, int kt){
    const int k0 = kt * BK;
    gl_lds16(srcA0 + k0, &As[buf][tid*8]);
    gl_lds16(srcA1 + k0, &As[buf][2048 + tid*8]);
    gl_lds16(srcB0 + k0, &Bs[buf][tid*8]);
    gl_lds16(srcB1 + k0, &Bs[buf][2048 + tid*8]);
  };

  auto compute = [&](int buf){
    bf16x8_t af[4], bfr[4];
    #pragma unroll
    for (int m=0;m<4;m++) af[m]  = *(const bf16x8_t*)&As[buf][offA[m]];
    #pragma unroll
    for (int n=0;n<4;n++) bfr[n] = *(const bf16x8_t*)&Bs[buf][offB[n]];
    #pragma unroll
    for (int m=0;m<4;m++){
      #pragma unroll
      for (int n=0;n<4;n++)
        acc[m][n] = __builtin_amdgcn_mfma_f32_16x16x32_bf16(af[m], bfr[n], acc[m][n], 0,0,0);
    }
  };

  constexpr int NS = DIMD/BK;   // 16
  stage(0,0); stage(1,1); stage(2,2);
  for (int t = 0; t + 4 <= NS; ++t){
    asm volatile("s_waitcnt vmcnt(8)" ::: "memory");
    __builtin_amdgcn_s_barrier();
    compute(t%3);
    __builtin_amdgcn_s_barrier();
    stage(t%3, t+3);
  }
  asm volatile("s_waitcnt vmcnt(8)" ::: "memory");
  __builtin_amdgcn_s_barrier();
  compute((NS-3)%3);
  asm volatile("s_waitcnt vmcnt(4)" ::: "memory");
  __builtin_amdgcn_s_barrier();
  compute((NS-2)%3);
  asm volatile("s_waitcnt vmcnt(0)" ::: "memory");
  __builtin_amdgcn_s_barrier();
  compute((NS-1)%3);

  const int r4 = (lane >> 4) * 4;
  #pragma unroll
  for (int n=0;n<4;n++){
    int hc = h0 + wc + n*16 + l15;
    float b1v = B1[(size_t)e*HIDH + hc];
    #pragma unroll
    for (int m=0;m<4;m++){
      int rbase = row0 + wr + m*16 + r4;
      #pragma unroll
      for (int r=0;r<4;r++){
        int row = rbase + r;
        if (row < cnt){
          float v = gelu_tanh(acc[m][n][r] + b1v);
          H[(size_t)(off + row)*HIDH + hc] = f2b(v);
        }
      }
    }
  }
}

// ---------------- GEMM2 (split-K): Yp[kc] = H[:, kc-chunk] . W2[kc-chunk, :] ----------------

__global__ __launch_bounds__(256,2) void gemm2(
    const unsigned short* __restrict__ H, const unsigned short* __restrict__ W2t,
    const int* __restrict__ meta, float* __restrict__ Y, int nsplit)
{
  const int e = blockIdx.z;
  const int cnt = meta[e];
  const int row0 = blockIdx.y * BM;
  if (row0 >= cnt) return;
  const int off = meta[16+e];
  const int ncol = DIMD/BN;
  const int d0 = (blockIdx.x % ncol) * BN;
  const int kc = blockIdx.x / ncol;
  const int kchunk = HIDH / nsplit;
  const int kbase = kc * kchunk;

  __shared__ unsigned short As[3][BM*BK];
  __shared__ unsigned short Bs[3][BN*BK];

  const int tid = threadIdx.x;
  const int ar0 = tid >> 2;
  const int ksw = (((tid & 3) ^ ((tid >> 3) & 3)) << 3);
  const unsigned short* srcA0 = H + (size_t)(off + row0 + ar0)*HIDH + kbase + ksw;
  const unsigned short* srcA1 = srcA0 + (size_t)64*HIDH;
  const unsigned short* srcB0 = W2t + ((size_t)e*DIMD + d0 + ar0)*HIDH + kbase + ksw;
  const unsigned short* srcB1 = srcB0 + (size_t)64*HIDH;

  const int lane = tid & 63;
  const int wid  = tid >> 6;
  const int wr = (wid >> 1) * 64, wc = (wid & 1) * 64;
  const int l15 = lane & 15, kg = lane >> 4;

  int offA[4], offB[4];
  #pragma unroll
  for (int m=0;m<4;m++){
    int r  = wr + m*16 + l15;
    int rb = wc + m*16 + l15;
    offA[m] = r *BK + ((kg ^ ((r >>1)&3)) << 3);
    offB[m] = rb*BK + ((kg ^ ((rb>>1)&3)) << 3);
  }

  f32x4_t acc[4][4];
  #pragma unroll
  for (int i=0;i<4;i++){
    #pragma unroll
    for (int j=0;j<4;j++) acc[i][j] = (f32x4_t){0.f,0.f,0.f,0.f};
  }

  auto stage = [&](int buf, int kt){
    const int k0 = kt * BK;
    gl_lds16(srcA0 + k0, &As[buf][tid*8]);
    gl_lds16(srcA1 + k0, &As[buf][2048 + tid*8]);
    gl_lds16(srcB0 + k0, &Bs[buf][tid*8]);
    gl_lds16(srcB1 + k0, &Bs[buf][2048 + tid*8]);
  };

  auto compute = [&](int buf){
    bf16x8_t af[4], bfr[4];
    #pragma unroll
    for (int m=0;m<4;m++) af[m]  = *(const bf16x8_t*)&As[buf][offA[m]];
    #pragma unroll
    for (int n=0;n<4;n++) bfr[n] = *(const bf16x8_t*)&Bs[buf][offB[n]];
    #pragma unroll
    for (int m=0;m<4;m++){
      #pragma unroll
      for (int n=0;n<4;n++)
        acc[m][n] = __builtin_amdgcn_mfma_f32_16x16x32_bf16(af[m], bfr[n], acc[m][n], 0,0,0);
    }
  };

  const int NS = kchunk / BK;   // 16/32/64 for nsplit 4/2/1
  stage(0,0); stage(1,1); stage(2,2);
  for (int t = 0; t + 4 <= NS; ++t){
    asm volatile("s_waitcnt vmcnt(8)" ::: "memory");
    __builtin_amdgcn_s_barrier();
    compute(t%3);
    __builtin_amdgcn_s_barrier();
    stage(t%3, t+3);
  }
  asm volatile("s_waitcnt vmcnt(8)" ::: "memory");
  __builtin_amdgcn_s_barrier();
  compute((NS-3)%3);
  asm volatile("s_waitcnt vmcnt(4)" ::: "memory");
  __builtin_amdgcn_s_barrier();
  compute((NS-2)%3);
  asm volatile("s_waitcnt vmcnt(0)" ::: "memory");
  __builtin_amdgcn_s_barrier();
  compute((NS-1)%3);

  float* Yp = Y + (size_t)kc * YROWS * DIMD;
  const int r4 = (lane >> 4) * 4;
  #pragma unroll
  for (int m=0;m<4;m++){
    int rbase = row0 + wr + m*16 + r4;
    #pragma unroll
    for (int r=0;r<4;r++){
      int row = rbase + r;
      if (row < cnt){
        float* yp = Yp + (size_t)(off + row)*DIMD + d0 + wc + l15;
        #pragma unroll
        for (int n=0;n<4;n++) yp[n*16] = acc[m][n][r];
      }
    }
  }
}

// ------- reduce: out[t] = sum_k P[t,k]*(sum_c Yc[row(t,k)] + b2[e]) -------

__global__ __launch_bounds__(128) void reduce_k(
    const float* __restrict__ P, const int* __restrict__ I, const int* __restrict__ rowOf,
    const float* __restrict__ Y, const float* __restrict__ B2, float* __restrict__ out,
    int nsplit)
{
  int t = blockIdx.x; int d4 = threadIdx.x;
  float4 a = make_float4(0.f,0.f,0.f,0.f);
  #pragma unroll
  for (int k=0;k<TOPK;k++){
    int i = t*TOPK + k;
    float p = P[i]; int e = I[i]; int r = rowOf[i];
    float4 b = *(const float4*)(B2 + (size_t)e*DIMD + d4*4);
    float4 y = make_float4(b.x, b.y, b.z, b.w);
    for (int c=0;c<nsplit;c++){
      float4 v = *(const float4*)(Y + (size_t)c*YROWS*DIMD + (size_t)r*DIMD + d4*4);
      y.x += v.x; y.y += v.y; y.z += v.z; y.w += v.w;
    }
    a.x = fmaf(p, y.x, a.x); a.y = fmaf(p, y.y, a.y);
    a.z = fmaf(p, y.z, a.z); a.w = fmaf(p, y.w, a.w);
  }
  *(float4*)(out + (size_t)t*DIMD + d4*4) = a;
}

// ================= fallback (round-1 f32 path, used if ws too small) =================

#define CAP (NTOK*TOPK)
#define ROWS 32
#define HC 64
#define NTHR 256
#define XS_LD 516
#define HS_LD 36

__global__ void fb_build(const int* __restrict__ idx, const float* __restrict__ probs,
                         int* __restrict__ counts, int* __restrict__ tok,
                         float* __restrict__ pr) {
    int i = blockIdx.x * blockDim.x + threadIdx.x;
    if (i >= NTOK * TOPK) return;
    int t = i / TOPK;
    int e = idx[i];
    float p = probs[i];
    int pos = atomicAdd(&counts[e], 1);
    tok[e * CAP + pos] = t;
    pr[e * CAP + pos] = p;
}

__global__ __launch_bounds__(NTHR)
void fb_moe(const float* __restrict__ X,
            const float* __restrict__ W1, const float* __restrict__ B1,
            const float* __restrict__ W2, const float* __restrict__ B2,
            const int* __restrict__ counts, const int* __restrict__ tok,
            const float* __restrict__ pr, float* __restrict__ out)
{
    const int e = blockIdx.y;
    const int cnt = counts[e];
    const int r0 = blockIdx.x * ROWS;
    if (r0 >= cnt) return;
    const int nr = min(ROWS, cnt - r0);

    extern __shared__ float smem[];
    float* Xs = smem;
    float* Hs = smem + ROWS * XS_LD;
    const int tid = threadIdx.x;

    for (int i = tid; i < ROWS * (DIMD / 4); i += NTHR) {
        int r = i >> 7;
        int c4 = i & 127;
        float4 v = make_float4(0.f, 0.f, 0.f, 0.f);
        if (r < nr) {
            int t = tok[e * CAP + r0 + r];
            v = *(const float4*)(X + (size_t)t * DIMD + c4 * 4);
        }
        *(float4*)(Xs + r * XS_LD + c4 * 4) = v;
    }
    __syncthreads();

    const int hq = tid & 15;
    const int rp = tid >> 4;
    const int wv = tid >> 6;
    const int ln = tid & 63;

    float yacc[8][8];
    #pragma unroll
    for (int r = 0; r < 8; ++r){
        #pragma unroll
        for (int c = 0; c < 8; ++c) yacc[r][c] = 0.f;
    }

    const float* w1base = W1 + (size_t)e * DIMD * HIDH;
    const float* w2base = W2 + (size_t)e * HIDH * DIMD;
    const float* b1base = B1 + e * HIDH;

    for (int h0 = 0; h0 < HIDH; h0 += HC) {
        float acc0[4] = {0.f, 0.f, 0.f, 0.f};
        float acc1[4] = {0.f, 0.f, 0.f, 0.f};
        const float* w1p = w1base + h0 + hq * 4;
        const float* xr0 = Xs + (rp * 2) * XS_LD;
        const float* xr1 = xr0 + XS_LD;
        #pragma unroll 2
        for (int d = 0; d < DIMD; d += 4) {
            float4 xa = *(const float4*)(xr0 + d);
            float4 xb = *(const float4*)(xr1 + d);
            float4 w0 = *(const float4*)(w1p + (size_t)(d + 0) * HIDH);
            float4 w1v = *(const float4*)(w1p + (size_t)(d + 1) * HIDH);
            float4 w2v = *(const float4*)(w1p + (size_t)(d + 2) * HIDH);
            float4 w3v = *(const float4*)(w1p + (size_t)(d + 3) * HIDH);
            float xav[4] = {xa.x, xa.y, xa.z, xa.w};
            float xbv[4] = {xb.x, xb.y, xb.z, xb.w};
            float4 wsv[4] = {w0, w1v, w2v, w3v};
            #pragma unroll
            for (int dd = 0; dd < 4; ++dd) {
                acc0[0] = fmaf(xav[dd], wsv[dd].x, acc0[0]);
                acc0[1] = fmaf(xav[dd], wsv[dd].y, acc0[1]);
                acc0[2] = fmaf(xav[dd], wsv[dd].z, acc0[2]);
                acc0[3] = fmaf(xav[dd], wsv[dd].w, acc0[3]);
                acc1[0] = fmaf(xbv[dd], wsv[dd].x, acc1[0]);
                acc1[1] = fmaf(xbv[dd], wsv[dd].y, acc1[1]);
                acc1[2] = fmaf(xbv[dd], wsv[dd].z, acc1[2]);
                acc1[3] = fmaf(xbv[dd], wsv[dd].w, acc1[3]);
            }
        }
        {
            float4 b1v = *(const float4*)(b1base + h0 + hq * 4);
            float bb[4] = {b1v.x, b1v.y, b1v.z, b1v.w};
            #pragma unroll
            for (int j = 0; j < 4; ++j) {
                Hs[(hq * 4 + j) * HS_LD + rp * 2]     = gelu_tanh(acc0[j] + bb[j]);
                Hs[(hq * 4 + j) * HS_LD + rp * 2 + 1] = gelu_tanh(acc1[j] + bb[j]);
            }
        }
        __syncthreads();

        const float* w2p = w2base + (size_t)h0 * DIMD;
        #pragma unroll 4
        for (int hc = 0; hc < HC; ++hc) {
            float4 wA = *(const float4*)(w2p + (size_t)hc * DIMD + ln * 4);
            float4 wB = *(const float4*)(w2p + (size_t)hc * DIMD + 256 + ln * 4);
            float4 hv0 = *(const float4*)(Hs + hc * HS_LD + wv * 8);
            float4 hv1 = *(const float4*)(Hs + hc * HS_LD + wv * 8 + 4);
            float hr[8] = {hv0.x, hv0.y, hv0.z, hv0.w, hv1.x, hv1.y, hv1.z, hv1.w};
            #pragma unroll
            for (int r = 0; r < 8; ++r) {
                yacc[r][0] = fmaf(hr[r], wA.x, yacc[r][0]);
                yacc[r][1] = fmaf(hr[r], wA.y, yacc[r][1]);
                yacc[r][2] = fmaf(hr[r], wA.z, yacc[r][2]);
                yacc[r][3] = fmaf(hr[r], wA.w, yacc[r][3]);
                yacc[r][4] = fmaf(hr[r], wB.x, yacc[r][4]);
                yacc[r][5] = fmaf(hr[r], wB.y, yacc[r][5]);
                yacc[r][6] = fmaf(hr[r], wB.z, yacc[r][6]);
                yacc[r][7] = fmaf(hr[r], wB.w, yacc[r][7]);
            }
        }
        __syncthreads();
    }

    const float* b2p = B2 + e * DIMD;
    float4 b2A = *(const float4*)(b2p + ln * 4);
    float4 b2B = *(const float4*)(b2p + 256 + ln * 4);
    float bA[4] = {b2A.x, b2A.y, b2A.z, b2A.w};
    float bB[4] = {b2B.x, b2B.y, b2B.z, b2B.w};
    #pragma unroll
    for (int r = 0; r < 8; ++r) {
        int rg = wv * 8 + r;
        if (rg < nr) {
            int t = tok[e * CAP + r0 + rg];
            float p = pr[e * CAP + r0 + rg];
            float* op = out + (size_t)t * DIMD;
            #pragma unroll
            for (int j = 0; j < 4; ++j) {
                atomicAdd(op + ln * 4 + j,        p * (yacc[r][j] + bA[j]));
                atomicAdd(op + 256 + ln * 4 + j,  p * (yacc[r][4 + j] + bB[j]));
            }
        }
    }
}

// ================= launch =================

extern "C" void kernel_launch(void* const* d_in, const int* in_sizes, int n_in,
                              void* d_out, int out_size, void* d_ws, size_t ws_size,
                              hipStream_t stream) {
    const float* X  = (const float*)d_in[0];
    const float* P  = (const float*)d_in[1];
    const int*   I  = (const int*)d_in[2];
    const float* W1 = (const float*)d_in[3];
    const float* B1 = (const float*)d_in[4];
    const float* W2 = (const float*)d_in[5];
    const float* B2 = (const float*)d_in[6];
    float* out = (float*)d_out;
    char* ws = (char*)d_ws;

    // ---- fast-path workspace layout; pick largest split-K that fits ----
    int nsplit = 0;
    size_t o_meta=0, o_tok=0, o_row=0, o_xb=0, o_w1t=0, o_w2t=0, o_h=0, o_y=0;
    const int cand[3] = {4, 2, 1};
    for (int ci = 0; ci < 3; ++ci) {
        int ns = cand[ci];
        size_t cur = 0;
        auto alloc = [&](size_t b){ size_t p = cur; cur += (b + 255) & ~(size_t)255; return p; };
        size_t m_ = alloc(256);
        size_t t_ = alloc((size_t)NSLOT*4);
        size_t r_ = alloc((size_t)NSLOT*4);
        size_t x_ = alloc((size_t)NTOK*DIMD*2);
        size_t w1_ = alloc((size_t)NEXP*DIMD*HIDH*2);
        size_t w2_ = alloc((size_t)NEXP*DIMD*HIDH*2);
        size_t h_ = alloc((size_t)YROWS*HIDH*2);
        size_t y_ = alloc((size_t)ns*YROWS*DIMD*4);
        if (cur <= ws_size) {
            nsplit = ns;
            o_meta=m_; o_tok=t_; o_row=r_; o_xb=x_; o_w1t=w1_; o_w2t=w2_; o_h=h_; o_y=y_;
            break;
        }
    }

    if (nsplit > 0) {
        int* meta = (int*)(ws + o_meta);
        int* tokOf = (int*)(ws + o_tok);
        int* rowOf = (int*)(ws + o_row);
        unsigned short* Xb  = (unsigned short*)(ws + o_xb);
        unsigned short* W1t = (unsigned short*)(ws + o_w1t);
        unsigned short* W2t = (unsigned short*)(ws + o_w2t);
        unsigned short* Hb  = (unsigned short*)(ws + o_h);
        float* Yb = (float*)(ws + o_y);

        hipMemsetAsync(meta, 0, 256, stream);
        cvt_x<<<(NTOK*DIMD/4 + 255)/256, 256, 0, stream>>>(X, Xb);
        transpose_cvt<<<dim3(HIDH/64, DIMD/64, NEXP), 256, 0, stream>>>(W1, W1t, DIMD, HIDH);
        transpose_cvt<<<dim3(DIMD/64, HIDH/64, NEXP), 256, 0, stream>>>(W2, W2t, HIDH, DIMD);
        count_k<<<NSLOT/256, 256, 0, stream>>>(I, meta);
        scan_k<<<1, 64, 0, stream>>>(meta);
        fill_k<<<NSLOT/256, 256, 0, stream>>>(I, meta, tokOf, rowOf);
        gemm1<<<dim3(HIDH/BN, NTOK/BM, NEXP), 256, 0, stream>>>(Xb, W1t, B1, meta, tokOf, Hb);
        gemm2<<<dim3((DIMD/BN)*nsplit, NTOK/BM, NEXP), 256, 0, stream>>>(Hb, W2t, meta, Yb, nsplit);
        reduce_k<<<NTOK, 128, 0, stream>>>(P, I, rowOf, Yb, B2, out, nsplit);
    } else {
        // fallback: round-1 f32 path
        int*   counts = (int*)ws;
        int*   tok    = (int*)(ws + 64);
        float* pr     = (float*)(ws + 64 + (size_t)NEXP * CAP * sizeof(int));

        hipMemsetAsync(counts, 0, NEXP * sizeof(int), stream);
        hipMemsetAsync(d_out, 0, (size_t)out_size * sizeof(float), stream);
        fb_build<<<(NTOK * TOPK + 255) / 256, 256, 0, stream>>>(I, P, counts, tok, pr);
        size_t smem = (size_t)(ROWS * XS_LD + HC * HS_LD) * sizeof(float);
        hipFuncSetAttribute((const void*)fb_moe,
                            hipFuncAttributeMaxDynamicSharedMemorySize, (int)smem);
        fb_moe<<<dim3(CAP / ROWS, NEXP), NTHR, smem, stream>>>(
            X, W1, B1, W2, B2, counts, tok, pr, out);
    }
}